// Round 1
// baseline (413.497 us; speedup 1.0000x reference)
//
#include <hip/hip_runtime.h>
#include <math.h>

#define B_   16
#define C_   64
#define C1_  8
#define C2_  32
#define HW_  4096
#define M_   1024

// ---------------------------------------------------------------------------
// K1: fused 1x1-conv (delta, phi, g) + 2x2 maxpool for phi/g.
// 65536 threads: gid -> (pos, pix); pos -> (b, m pooled); pix -> 2x2 corner.
// Pooling via __shfl_xor over lane quads (pix lives in tid bits 0..1).
// phi is stored PRE-SCRAMBLED per the reference's transpose(1,0,2,3).reshape:
//   slot f = b*8 + c1 reads pooled[b = f&15][ch = f>>4][m];
//   writer computes pooled[b_w][cp][m] -> writes slot f = cp*16 + b_w.
// Layouts: delta_buf[b][n][8], phi_buf[b][m][8], g_buf[b][m][32].
// ---------------------------------------------------------------------------
__global__ __launch_bounds__(256)
void k_pre(const float* __restrict__ x,
           const float* __restrict__ w_delta, const float* __restrict__ b_delta,
           const float* __restrict__ w_phi,  const float* __restrict__ b_phi,
           const float* __restrict__ w_g,    const float* __restrict__ b_g,
           float* __restrict__ delta_buf, float* __restrict__ phi_buf,
           float* __restrict__ g_buf) {
  // weights transposed in LDS -> contiguous per-c rows -> ds_read_b128
  __shared__ float wd_s[C_*C1_];  // [c][o]
  __shared__ float wp_s[C_*C1_];
  __shared__ float wg_s[C_*C2_];
  int tid = threadIdx.x;
  for (int i = tid; i < C1_*C_; i += 256) {
    int o = i >> 6, c = i & 63;
    wd_s[c*C1_ + o] = w_delta[i];
    wp_s[c*C1_ + o] = w_phi[i];
  }
  for (int i = tid; i < C2_*C_; i += 256) {
    int o = i >> 6, c = i & 63;
    wg_s[c*C2_ + o] = w_g[i];
  }
  __syncthreads();

  int gid = blockIdx.x * 256 + tid;   // 0..65535
  int pix = gid & 3;                  // 2x2 corner (in low lane bits!)
  int pos = gid >> 2;                 // 0..16383
  int b = pos >> 10;
  int m = pos & 1023;                 // pooled position
  int ph = m >> 5, pw = m & 31;
  int py = 2*ph + (pix >> 1);
  int px = 2*pw + (pix & 1);
  int n = py * 64 + px;               // full-res position

  const float* xp = x + (size_t)b * C_ * HW_ + n;

  float ad[C1_], ap[C1_], ag[C2_];
  #pragma unroll
  for (int o = 0; o < C1_; ++o) { ad[o] = 0.f; ap[o] = 0.f; }
  #pragma unroll
  for (int o = 0; o < C2_; ++o) ag[o] = 0.f;

  for (int c = 0; c < C_; ++c) {
    float xv = xp[(size_t)c * HW_];
    #pragma unroll
    for (int v = 0; v < 2; ++v) {
      float4 t = ((const float4*)(wd_s + c*C1_))[v];
      ad[4*v+0] += xv*t.x; ad[4*v+1] += xv*t.y; ad[4*v+2] += xv*t.z; ad[4*v+3] += xv*t.w;
    }
    #pragma unroll
    for (int v = 0; v < 2; ++v) {
      float4 t = ((const float4*)(wp_s + c*C1_))[v];
      ap[4*v+0] += xv*t.x; ap[4*v+1] += xv*t.y; ap[4*v+2] += xv*t.z; ap[4*v+3] += xv*t.w;
    }
    #pragma unroll
    for (int v = 0; v < 8; ++v) {
      float4 t = ((const float4*)(wg_s + c*C2_))[v];
      ag[4*v+0] += xv*t.x; ag[4*v+1] += xv*t.y; ag[4*v+2] += xv*t.z; ag[4*v+3] += xv*t.w;
    }
  }

  // delta: every thread owns one full-res row (b, n)
  {
    float4* dp = (float4*)(delta_buf + ((size_t)b * HW_ + n) * C1_);
    dp[0] = make_float4(ad[0]+b_delta[0], ad[1]+b_delta[1],
                        ad[2]+b_delta[2], ad[3]+b_delta[3]);
    dp[1] = make_float4(ad[4]+b_delta[4], ad[5]+b_delta[5],
                        ad[6]+b_delta[6], ad[7]+b_delta[7]);
  }

  // 2x2 maxpool across the lane quad
  #pragma unroll
  for (int o = 0; o < C1_; ++o) {
    float v = ap[o];
    v = fmaxf(v, __shfl_xor(v, 1));
    v = fmaxf(v, __shfl_xor(v, 2));
    ap[o] = v;
  }
  #pragma unroll
  for (int o = 0; o < C2_; ++o) {
    float v = ag[o];
    v = fmaxf(v, __shfl_xor(v, 1));
    v = fmaxf(v, __shfl_xor(v, 2));
    ag[o] = v;
  }

  if ((tid & 3) == 0) {
    #pragma unroll
    for (int cp = 0; cp < C1_; ++cp) {      // scrambled phi write
      int f = cp * 16 + b;
      phi_buf[((size_t)(f >> 3) * M_ + m) * C1_ + (f & 7)] = ap[cp] + b_phi[cp];
    }
    float4* gp = (float4*)(g_buf + ((size_t)b * M_ + m) * C2_);
    #pragma unroll
    for (int v = 0; v < 8; ++v)
      gp[v] = make_float4(ag[4*v+0]+b_g[4*v+0], ag[4*v+1]+b_g[4*v+1],
                          ag[4*v+2]+b_g[4*v+2], ag[4*v+3]+b_g[4*v+3]);
  }
}

// ---------------------------------------------------------------------------
// K2: flash attention (no-max softmax: logits bounded ~|25|, exp can't
// overflow fp32) + fused last conv + gamma + residual.
// Block = 256 thr (4 waves). wave&1 = row half (64 rows each),
// wave>>1 = key half (512 keys each). One lane per Q-row.
// phi/g addresses are wave-uniform -> scalar (broadcast) loads.
// ---------------------------------------------------------------------------
__global__ __launch_bounds__(256)
void k_attn(const float* __restrict__ x,
            const float* __restrict__ delta_buf,
            const float* __restrict__ phi_buf,
            const float* __restrict__ g_buf,
            const float* __restrict__ w_last,
            const float* __restrict__ b_last,
            const float* __restrict__ gamma,
            float* __restrict__ out) {
  __shared__ float part[128 * 33];   // stride 33: bank-conflict-free
  int tid = threadIdx.x;
  int lane = tid & 63;
  int wave = tid >> 6;
  int rh = wave & 1;
  int kh = wave >> 1;
  int bx = blockIdx.x;               // 0..511
  int b = bx >> 5;
  int n0 = (bx & 31) * 128;
  int r = rh * 64 + lane;            // local row 0..127
  int n = n0 + r;

  const float4* dp = (const float4*)(delta_buf + ((size_t)b * HW_ + n) * C1_);
  float4 d0 = dp[0], d1 = dp[1];
  float d[8] = {d0.x, d0.y, d0.z, d0.w, d1.x, d1.y, d1.z, d1.w};

  float acc[C2_];
  #pragma unroll
  for (int c = 0; c < C2_; ++c) acc[c] = 0.f;
  float den = 0.f;

  const float* phib = phi_buf + (size_t)b * M_ * C1_;
  const float* gb   = g_buf   + (size_t)b * M_ * C2_;

  int m0 = kh * 512;
  #pragma unroll 2
  for (int mm = 0; mm < 512; ++mm) {
    int m = m0 + mm;
    const float4* pc = (const float4*)(phib + (size_t)m * C1_);
    float4 p0 = pc[0], p1 = pc[1];
    float logit = d[0]*p0.x + d[1]*p0.y + d[2]*p0.z + d[3]*p0.w
                + d[4]*p1.x + d[5]*p1.y + d[6]*p1.z + d[7]*p1.w;
    float p = __expf(logit);
    den += p;
    const float4* gr = (const float4*)(gb + (size_t)m * C2_);
    #pragma unroll
    for (int v = 0; v < 8; ++v) {
      float4 gv = gr[v];
      acc[4*v+0] += p * gv.x;
      acc[4*v+1] += p * gv.y;
      acc[4*v+2] += p * gv.z;
      acc[4*v+3] += p * gv.w;
    }
  }

  // combine the two key-halves
  if (kh == 1) {
    #pragma unroll
    for (int c = 0; c < C2_; ++c) part[r * 33 + c] = acc[c];
    part[r * 33 + 32] = den;
  }
  __syncthreads();
  if (kh == 0) {
    #pragma unroll
    for (int c = 0; c < C2_; ++c) acc[c] += part[r * 33 + c];
    den += part[r * 33 + 32];
    float inv = 1.0f / den;
    #pragma unroll
    for (int c = 0; c < C2_; ++c) part[r * 33 + c] = acc[c] * inv;
  }
  __syncthreads();

  // epilogue: out[b,co,n] = gamma * (w_last[co,:] . o[n,:] + b_last[co]) + x
  // rr = tid&127 constant per thread; co = 2i + (tid>>7) wave-uniform.
  int rr = tid & 127;
  float o_reg[C2_];
  #pragma unroll
  for (int c = 0; c < C2_; ++c) o_reg[c] = part[rr * 33 + c];
  float gm = gamma[0];
  for (int i = 0; i < 32; ++i) {
    int co = 2 * i + (tid >> 7);
    float a = b_last[co];
    #pragma unroll
    for (int c = 0; c < C2_; ++c) a += w_last[co * C2_ + c] * o_reg[c];
    size_t oi = ((size_t)b * C_ + co) * HW_ + (size_t)(n0 + rr);
    out[oi] = gm * a + x[oi];
  }
}

// ---------------------------------------------------------------------------
extern "C" void kernel_launch(void* const* d_in, const int* in_sizes, int n_in,
                              void* d_out, int out_size, void* d_ws, size_t ws_size,
                              hipStream_t stream) {
  const float* x       = (const float*)d_in[0];
  const float* w_delta = (const float*)d_in[1];
  const float* b_delta = (const float*)d_in[2];
  const float* w_phi   = (const float*)d_in[3];
  const float* b_phi   = (const float*)d_in[4];
  const float* w_g     = (const float*)d_in[5];
  const float* b_g     = (const float*)d_in[6];
  const float* w_last  = (const float*)d_in[7];
  const float* b_last  = (const float*)d_in[8];
  const float* gamma   = (const float*)d_in[9];
  float* out = (float*)d_out;

  float* ws = (float*)d_ws;
  float* delta_buf = ws;                         // 16*4096*8  = 524288 f
  float* phi_buf   = ws + 524288;                // 16*1024*8  = 131072 f
  float* g_buf     = ws + 524288 + 131072;       // 16*1024*32 = 524288 f
  // total 4.5 MB of workspace

  hipLaunchKernelGGL(k_pre, dim3(256), dim3(256), 0, stream,
                     x, w_delta, b_delta, w_phi, b_phi, w_g, b_g,
                     delta_buf, phi_buf, g_buf);
  hipLaunchKernelGGL(k_attn, dim3(512), dim3(256), 0, stream,
                     x, delta_buf, phi_buf, g_buf, w_last, b_last, gamma, out);
}

// Round 2
// 152.769 us; speedup vs baseline: 2.7067x; 2.7067x over previous
//
#include <hip/hip_runtime.h>
#include <math.h>

typedef __attribute__((ext_vector_type(8))) short bf16x8;
typedef __attribute__((ext_vector_type(4))) float f32x4;

#define B_   16
#define C_   64
#define C1_  8
#define C2_  32
#define HW_  4096
#define M_   1024
#define LOG2E 1.4426950408889634f

__device__ __forceinline__ unsigned short f2bf(float f) {
  union { float f; unsigned u; } v; v.f = f;
  unsigned r = (v.u + 0x7fffu + ((v.u >> 16) & 1u)) >> 16;
  return (unsigned short)r;
}
__device__ __forceinline__ float bf2f(unsigned short h) {
  union { unsigned u; float f; } v; v.u = ((unsigned)h) << 16;
  return v.f;
}

// ---------------------------------------------------------------------------
// K1: fused 1x1-convs + 2x2 maxpool, bf16 outputs for the MFMA attention.
//   delta_s[b][n][16]  : [dh(8) dl(8)]   hi/lo bf16 split of (conv+bias)*log2e
//   phi_s [b][m][16]   : [ph(8) pl(8)]   hi/lo split, batch/channel scrambled
//   g_t   [b][c2][m]   : bf16 (transposed for PV B-frag reads)
// 512 blocks x 256 thr; channel-split 2-way (tid>>7) combined through LDS
// -> 2 waves/SIMD (was 1).
// ---------------------------------------------------------------------------
__global__ __launch_bounds__(256)
void k_pre(const float* __restrict__ x,
           const float* __restrict__ w_delta, const float* __restrict__ b_delta,
           const float* __restrict__ w_phi,  const float* __restrict__ b_phi,
           const float* __restrict__ w_g,    const float* __restrict__ b_g,
           unsigned short* __restrict__ delta_s,
           unsigned short* __restrict__ phi_s,
           unsigned short* __restrict__ g_t) {
  __shared__ float wd_s[C_*C1_];   // [c][o]
  __shared__ float wp_s[C_*C1_];
  __shared__ float wg_s[C_*C2_];
  __shared__ float comb[128*49];   // stride 49 (odd) -> conflict-free b32
  int tid = threadIdx.x;
  for (int i = tid; i < C1_*C_; i += 256) {
    int o = i >> 6, c = i & 63;
    wd_s[c*C1_ + o] = w_delta[i];
    wp_s[c*C1_ + o] = w_phi[i];
  }
  for (int i = tid; i < C2_*C_; i += 256) {
    int o = i >> 6, c = i & 63;
    wg_s[c*C2_ + o] = w_g[i];
  }
  __syncthreads();

  int half = tid >> 7;             // channel half
  int sub  = tid & 127;
  int pix  = sub & 3;              // 2x2 corner (lane bits 0..1)
  int posL = sub >> 2;
  int pos  = blockIdx.x * 32 + posL;
  int b = pos >> 10;
  int m = pos & 1023;
  int py = 2*(m >> 5) + (pix >> 1);
  int px = 2*(m & 31) + (pix & 1);
  int n = py * 64 + px;

  // preload this thread's 32 x values (independent loads -> deep ILP)
  const float* xp = x + ((size_t)b*C_ + half*32)*HW_ + n;
  float xv[32];
  #pragma unroll
  for (int i = 0; i < 32; ++i) xv[i] = xp[(size_t)i * HW_];

  float ad[8], ap[8], ag[32];
  #pragma unroll
  for (int o = 0; o < 8; ++o) { ad[o] = 0.f; ap[o] = 0.f; }
  #pragma unroll
  for (int o = 0; o < 32; ++o) ag[o] = 0.f;

  int c0 = half * 32;
  #pragma unroll
  for (int i = 0; i < 32; ++i) {
    int c = c0 + i;
    float v = xv[i];
    #pragma unroll
    for (int t = 0; t < 2; ++t) {
      float4 w = ((const float4*)(wd_s + c*C1_))[t];
      ad[4*t+0] += v*w.x; ad[4*t+1] += v*w.y; ad[4*t+2] += v*w.z; ad[4*t+3] += v*w.w;
    }
    #pragma unroll
    for (int t = 0; t < 2; ++t) {
      float4 w = ((const float4*)(wp_s + c*C1_))[t];
      ap[4*t+0] += v*w.x; ap[4*t+1] += v*w.y; ap[4*t+2] += v*w.z; ap[4*t+3] += v*w.w;
    }
    #pragma unroll
    for (int t = 0; t < 8; ++t) {
      float4 w = ((const float4*)(wg_s + c*C2_))[t];
      ag[4*t+0] += v*w.x; ag[4*t+1] += v*w.y; ag[4*t+2] += v*w.z; ag[4*t+3] += v*w.w;
    }
  }

  if (half == 1) {
    float* cb = comb + sub*49;
    #pragma unroll
    for (int o = 0; o < 8; ++o) { cb[o] = ad[o]; cb[8+o] = ap[o]; }
    #pragma unroll
    for (int o = 0; o < 32; ++o) cb[16+o] = ag[o];
  }
  __syncthreads();
  if (half == 0) {
    const float* cb = comb + sub*49;
    #pragma unroll
    for (int o = 0; o < 8; ++o) { ad[o] += cb[o]; ap[o] += cb[8+o]; }
    #pragma unroll
    for (int o = 0; o < 32; ++o) ag[o] += cb[16+o];

    // delta: full-res, scaled by log2e, hi/lo split
    __align__(16) unsigned short row[16];
    #pragma unroll
    for (int o = 0; o < 8; ++o) {
      float v = (ad[o] + b_delta[o]) * LOG2E;
      unsigned short hi = f2bf(v);
      row[o]   = hi;
      row[8+o] = f2bf(v - bf2f(hi));
    }
    uint4* dst = (uint4*)(delta_s + ((size_t)b*HW_ + n)*16);
    dst[0] = *(uint4*)&row[0];
    dst[1] = *(uint4*)&row[8];

    // 2x2 maxpool over the lane quad (waves 0/1 fully active here)
    #pragma unroll
    for (int o = 0; o < 8; ++o) {
      float v = ap[o];
      v = fmaxf(v, __shfl_xor(v, 1));
      v = fmaxf(v, __shfl_xor(v, 2));
      ap[o] = v;
    }
    #pragma unroll
    for (int o = 0; o < 32; ++o) {
      float v = ag[o];
      v = fmaxf(v, __shfl_xor(v, 1));
      v = fmaxf(v, __shfl_xor(v, 2));
      ag[o] = v;
    }

    if ((sub & 3) == 0) {
      // phi: scrambled slot f = cp*16 + b -> buffer batch f>>3, channel f&7
      #pragma unroll
      for (int cp = 0; cp < 8; ++cp) {
        int f = cp*16 + b;
        float v = ap[cp] + b_phi[cp];
        unsigned short hi = f2bf(v);
        unsigned short* pr = phi_s + ((size_t)(f >> 3)*M_ + m)*16;
        pr[f & 7]       = hi;
        pr[8 + (f & 7)] = f2bf(v - bf2f(hi));
      }
      // g transposed: [b][c2][m]
      #pragma unroll
      for (int o = 0; o < 32; ++o)
        g_t[((size_t)b*C2_ + o)*M_ + m] = f2bf(ag[o] + b_g[o]);
    }
  }
}

// ---------------------------------------------------------------------------
// K2: MFMA flash attention (no-max softmax) + fused last conv + residual.
// 1024 blocks x 256 thr; wave = one 16-row Q-tile; no barriers in key loop.
// Per 32-key chunk: 2x QK mfma_16x16x32_bf16 (hi/lo split packed in K) ->
// exp2 -> E (C-layout == PV A-layout, key order permuted) -> 2x PV mfma.
// ---------------------------------------------------------------------------
__global__ __launch_bounds__(256, 4)
void k_attn(const float* __restrict__ x,
            const unsigned short* __restrict__ delta_s,
            const unsigned short* __restrict__ phi_s,
            const unsigned short* __restrict__ g_t,
            const float* __restrict__ w_last,
            const float* __restrict__ b_last,
            const float* __restrict__ gamma,
            float* __restrict__ out) {
  __shared__ float o_sh[64*33];
  int tid  = threadIdx.x;
  int lane = tid & 63;
  int wv   = tid >> 6;
  int r    = lane & 15;
  int q    = lane >> 4;
  int bx = blockIdx.x;
  int b  = bx >> 6;
  int n0 = (bx & 63) * 64;

  // B-frag (QK): delta row = this lane's Q-row; k-slots [dh dl dh dl]
  int qrow = n0 + wv*16 + r;
  bf16x8 dfrag = *(const bf16x8*)(delta_s + ((size_t)b*HW_ + qrow)*16 + (q & 1)*8);

  const unsigned short* phib = phi_s + (size_t)b*M_*16;
  const unsigned short* gb0  = g_t + ((size_t)b*C2_ + r)      * M_;
  const unsigned short* gb1  = g_t + ((size_t)b*C2_ + 16 + r) * M_;
  int phi_off = (q >> 1) * 8;               // [ph ph pl pl] across k
  int key0 = (r >> 2)*8 + (r & 3);          // permuted so S-tile C-layout
  int key1 = key0 + 4;                      // concatenates into PV A-frag

  f32x4 acc0 = {0.f,0.f,0.f,0.f}, acc1 = {0.f,0.f,0.f,0.f};
  f32x4 zero = {0.f,0.f,0.f,0.f};
  float den = 0.f;

  #pragma unroll 4
  for (int k0 = 0; k0 < M_; k0 += 32) {
    bf16x8 aphi0 = *(const bf16x8*)(phib + (size_t)(k0 + key0)*16 + phi_off);
    bf16x8 aphi1 = *(const bf16x8*)(phib + (size_t)(k0 + key1)*16 + phi_off);
    bf16x8 bg0   = *(const bf16x8*)(gb0 + k0 + q*8);
    bf16x8 bg1   = *(const bf16x8*)(gb1 + k0 + q*8);

    f32x4 s0 = __builtin_amdgcn_mfma_f32_16x16x32_bf16(aphi0, dfrag, zero, 0, 0, 0);
    f32x4 s1 = __builtin_amdgcn_mfma_f32_16x16x32_bf16(aphi1, dfrag, zero, 0, 0, 0);

    float e0 = __builtin_amdgcn_exp2f(s0[0]);
    float e1 = __builtin_amdgcn_exp2f(s0[1]);
    float e2 = __builtin_amdgcn_exp2f(s0[2]);
    float e3 = __builtin_amdgcn_exp2f(s0[3]);
    float e4 = __builtin_amdgcn_exp2f(s1[0]);
    float e5 = __builtin_amdgcn_exp2f(s1[1]);
    float e6 = __builtin_amdgcn_exp2f(s1[2]);
    float e7 = __builtin_amdgcn_exp2f(s1[3]);
    den += (e0+e1) + (e2+e3) + (e4+e5) + (e6+e7);

    bf16x8 efrag;
    efrag[0] = (short)f2bf(e0); efrag[1] = (short)f2bf(e1);
    efrag[2] = (short)f2bf(e2); efrag[3] = (short)f2bf(e3);
    efrag[4] = (short)f2bf(e4); efrag[5] = (short)f2bf(e5);
    efrag[6] = (short)f2bf(e6); efrag[7] = (short)f2bf(e7);

    acc0 = __builtin_amdgcn_mfma_f32_16x16x32_bf16(efrag, bg0, acc0, 0, 0, 0);
    acc1 = __builtin_amdgcn_mfma_f32_16x16x32_bf16(efrag, bg1, acc1, 0, 0, 0);
  }

  // den: lane holds partial for Q-row r over its q-group's keys
  float d1 = den + __shfl_xor(den, 16);
  float den_full = d1 + __shfl_xor(d1, 32);   // full den for row r, all lanes

  // acc rows are q*4+reg -> fetch matching den via bpermute, write O to LDS
  #pragma unroll
  for (int reg = 0; reg < 4; ++reg) {
    float dv = __shfl(den_full, q*4 + reg);   // den of row q*4+reg
    float iv = 1.0f / dv;
    int rl = wv*16 + q*4 + reg;
    o_sh[rl*33 + r]      = acc0[reg] * iv;
    o_sh[rl*33 + 16 + r] = acc1[reg] * iv;
  }
  __syncthreads();

  // epilogue: out[b,co,n0+rr] = gamma*(w_last[co,:].O[rr,:] + b_last[co]) + x
  int rr = tid & 63;
  int wq = tid >> 6;
  float o_reg[32];
  #pragma unroll
  for (int c = 0; c < 32; ++c) o_reg[c] = o_sh[rr*33 + c];
  float gm = gamma[0];
  for (int i = 0; i < 16; ++i) {
    int co = wq*16 + i;                        // wave-uniform -> scalar loads
    float a = b_last[co];
    #pragma unroll
    for (int c = 0; c < 32; ++c) a += w_last[co*32 + c] * o_reg[c];
    size_t oi = ((size_t)b*C_ + co)*HW_ + (size_t)(n0 + rr);
    out[oi] = gm * a + x[oi];
  }
}

// ---------------------------------------------------------------------------
extern "C" void kernel_launch(void* const* d_in, const int* in_sizes, int n_in,
                              void* d_out, int out_size, void* d_ws, size_t ws_size,
                              hipStream_t stream) {
  const float* x       = (const float*)d_in[0];
  const float* w_delta = (const float*)d_in[1];
  const float* b_delta = (const float*)d_in[2];
  const float* w_phi   = (const float*)d_in[3];
  const float* b_phi   = (const float*)d_in[4];
  const float* w_g     = (const float*)d_in[5];
  const float* b_g     = (const float*)d_in[6];
  const float* w_last  = (const float*)d_in[7];
  const float* b_last  = (const float*)d_in[8];
  const float* gamma   = (const float*)d_in[9];
  float* out = (float*)d_out;

  unsigned short* ws = (unsigned short*)d_ws;
  unsigned short* delta_s = ws;                         // 16*4096*16 = 1,048,576 us (2 MB)
  unsigned short* phi_s   = ws + (size_t)B_*HW_*16;     // 16*1024*16 =   262,144 us (0.5 MB)
  unsigned short* g_t     = phi_s + (size_t)B_*M_*16;   // 16*32*1024 =   524,288 us (1 MB)

  hipLaunchKernelGGL(k_pre, dim3(512), dim3(256), 0, stream,
                     x, w_delta, b_delta, w_phi, b_phi, w_g, b_g,
                     delta_s, phi_s, g_t);
  hipLaunchKernelGGL(k_attn, dim3(1024), dim3(256), 0, stream,
                     x, delta_s, phi_s, g_t, w_last, b_last, gamma, out);
}

// Round 3
// 135.096 us; speedup vs baseline: 3.0608x; 1.1308x over previous
//
#include <hip/hip_runtime.h>
#include <hip/hip_bf16.h>
#include <math.h>

typedef __attribute__((ext_vector_type(8))) short bf16x8;
typedef __attribute__((ext_vector_type(4))) float f32x4;

#define B_   16
#define C_   64
#define C1_  8
#define C2_  32
#define HW_  4096
#define M_   1024
#define LOG2E 1.4426950408889634f
#define MFMA_BF16 __builtin_amdgcn_mfma_f32_16x16x32_bf16

__device__ __forceinline__ unsigned short f2bf(float f) {
  union { float f; unsigned u; } v; v.f = f;
  unsigned r = (v.u + 0x7fffu + ((v.u >> 16) & 1u)) >> 16;
  return (unsigned short)r;
}
__device__ __forceinline__ float bf2f(unsigned short h) {
  union { unsigned u; float f; } v; v.u = ((unsigned)h) << 16;
  return v.f;
}

// ---------------------------------------------------------------------------
// K1: fused 1x1-convs + 2x2 maxpool, bf16 outputs for the MFMA attention.
//   delta_s[b][n][16] : [dh(8) dl(8)] hi/lo bf16 split of (conv+bias)*log2e
//   phi_s [b][m][16]  : [ph(8) pl(8)] hi/lo split, batch/channel scrambled
//   g_t   [b][c2][m]  : bf16 (transposed for PV B-frag reads)
// v3: 4-way channel split (wave = channel quarter), 1024 blocks x 256 thr
// -> 4 blocks/CU, 4 waves/SIMD (was 2). Partials combined via LDS in 3
// rounds; wave 0 does pooling + writes.
// ---------------------------------------------------------------------------
__global__ __launch_bounds__(256, 4)
void k_pre(const float* __restrict__ x,
           const float* __restrict__ w_delta, const float* __restrict__ b_delta,
           const float* __restrict__ w_phi,  const float* __restrict__ b_phi,
           const float* __restrict__ w_g,    const float* __restrict__ b_g,
           unsigned short* __restrict__ delta_s,
           unsigned short* __restrict__ phi_s,
           unsigned short* __restrict__ g_t) {
  __shared__ float wd_s[C_*C1_];   // [c][o]
  __shared__ float wp_s[C_*C1_];
  __shared__ float wg_s[C_*C2_];
  __shared__ float comb[2*64*49];  // 2 regions, stride 49 -> 2-way (free)
  int tid = threadIdx.x;
  for (int i = tid; i < C1_*C_; i += 256) {
    int o = i >> 6, c = i & 63;
    wd_s[c*C1_ + o] = w_delta[i];
    wp_s[c*C1_ + o] = w_phi[i];
  }
  for (int i = tid; i < C2_*C_; i += 256) {
    int o = i >> 6, c = i & 63;
    wg_s[c*C2_ + o] = w_g[i];
  }
  __syncthreads();

  int qt  = tid >> 6;              // channel quarter == wave index
  int sub = tid & 63;
  int id  = blockIdx.x * 64 + sub; // pixel id 0..65535
  int pix = id & 3;                // 2x2 corner (lane bits 0..1)
  int pm  = id >> 2;
  int b = pm >> 10;
  int m = pm & 1023;
  int py = 2*(m >> 5) + (pix >> 1);
  int px = 2*(m & 31) + (pix & 1);
  int n = py * 64 + px;

  // 16 independent x loads -> deep MLP
  const float* xp = x + ((size_t)b*C_ + qt*16)*HW_ + n;
  float xv[16];
  #pragma unroll
  for (int i = 0; i < 16; ++i) xv[i] = xp[(size_t)i * HW_];

  float ad[8], ap[8], ag[32];
  #pragma unroll
  for (int o = 0; o < 8; ++o) { ad[o] = 0.f; ap[o] = 0.f; }
  #pragma unroll
  for (int o = 0; o < 32; ++o) ag[o] = 0.f;

  int c0 = qt * 16;
  #pragma unroll
  for (int i = 0; i < 16; ++i) {
    int c = c0 + i;
    float v = xv[i];
    #pragma unroll
    for (int t = 0; t < 2; ++t) {
      float4 w = ((const float4*)(wd_s + c*C1_))[t];
      ad[4*t+0] += v*w.x; ad[4*t+1] += v*w.y; ad[4*t+2] += v*w.z; ad[4*t+3] += v*w.w;
    }
    #pragma unroll
    for (int t = 0; t < 2; ++t) {
      float4 w = ((const float4*)(wp_s + c*C1_))[t];
      ap[4*t+0] += v*w.x; ap[4*t+1] += v*w.y; ap[4*t+2] += v*w.z; ap[4*t+3] += v*w.w;
    }
    #pragma unroll
    for (int t = 0; t < 8; ++t) {
      float4 w = ((const float4*)(wg_s + c*C2_))[t];
      ag[4*t+0] += v*w.x; ag[4*t+1] += v*w.y; ag[4*t+2] += v*w.z; ag[4*t+3] += v*w.w;
    }
  }

  // combine quarters: q1->reg0, q3->reg1; q0+=reg0, q2+=reg1; q2->reg0; q0+=reg0
  if (qt == 1 || qt == 3) {
    float* cb = comb + (((qt >> 1)*64) + sub)*49;
    #pragma unroll
    for (int o = 0; o < 8; ++o) { cb[o] = ad[o]; cb[8+o] = ap[o]; }
    #pragma unroll
    for (int o = 0; o < 32; ++o) cb[16+o] = ag[o];
  }
  __syncthreads();
  if (qt == 0 || qt == 2) {
    const float* cb = comb + (((qt >> 1)*64) + sub)*49;
    #pragma unroll
    for (int o = 0; o < 8; ++o) { ad[o] += cb[o]; ap[o] += cb[8+o]; }
    #pragma unroll
    for (int o = 0; o < 32; ++o) ag[o] += cb[16+o];
  }
  __syncthreads();
  if (qt == 2) {
    float* cb = comb + sub*49;
    #pragma unroll
    for (int o = 0; o < 8; ++o) { cb[o] = ad[o]; cb[8+o] = ap[o]; }
    #pragma unroll
    for (int o = 0; o < 32; ++o) cb[16+o] = ag[o];
  }
  __syncthreads();
  if (qt == 0) {
    const float* cb = comb + sub*49;
    #pragma unroll
    for (int o = 0; o < 8; ++o) { ad[o] += cb[o]; ap[o] += cb[8+o]; }
    #pragma unroll
    for (int o = 0; o < 32; ++o) ag[o] += cb[16+o];

    // delta: full-res, scaled by log2e, hi/lo split
    __align__(16) unsigned short row[16];
    #pragma unroll
    for (int o = 0; o < 8; ++o) {
      float v = (ad[o] + b_delta[o]) * LOG2E;
      unsigned short hi = f2bf(v);
      row[o]   = hi;
      row[8+o] = f2bf(v - bf2f(hi));
    }
    uint4* dst = (uint4*)(delta_s + ((size_t)b*HW_ + n)*16);
    dst[0] = *(uint4*)&row[0];
    dst[1] = *(uint4*)&row[8];

    // 2x2 maxpool over the lane quad (pix lives in lane bits 0..1)
    #pragma unroll
    for (int o = 0; o < 8; ++o) {
      float v = ap[o];
      v = fmaxf(v, __shfl_xor(v, 1));
      v = fmaxf(v, __shfl_xor(v, 2));
      ap[o] = v;
    }
    #pragma unroll
    for (int o = 0; o < 32; ++o) {
      float v = ag[o];
      v = fmaxf(v, __shfl_xor(v, 1));
      v = fmaxf(v, __shfl_xor(v, 2));
      ag[o] = v;
    }

    if ((sub & 3) == 0) {
      // phi: scrambled slot f = cp*16 + b -> buffer batch f>>3, channel f&7
      #pragma unroll
      for (int cp = 0; cp < 8; ++cp) {
        int f = cp*16 + b;
        float v = ap[cp] + b_phi[cp];
        unsigned short hi = f2bf(v);
        unsigned short* pr = phi_s + ((size_t)(f >> 3)*M_ + m)*16;
        pr[f & 7]       = hi;
        pr[8 + (f & 7)] = f2bf(v - bf2f(hi));
      }
      // g transposed: [b][c2][m]
      #pragma unroll
      for (int o = 0; o < 32; ++o)
        g_t[((size_t)b*C2_ + o)*M_ + m] = f2bf(ag[o] + b_g[o]);
    }
  }
}

// ---------------------------------------------------------------------------
// K2: MFMA flash attention (no-max softmax) + fused last conv + residual.
// v3: wave = 32 Q-rows (2 tiles sharing phi/g loads), keys split 2-way
// across waves (combined via LDS), den via MFMA against a ones-fragment
// (lands pre-aligned with acc rows -> no shuffles), E packed with
// v_cvt_pk_bf16_f32. 1024 blocks x 256 thr -> 4 blocks/CU.
// ---------------------------------------------------------------------------
__global__ __launch_bounds__(256, 4)
void k_attn(const float* __restrict__ x,
            const unsigned short* __restrict__ delta_s,
            const unsigned short* __restrict__ phi_s,
            const unsigned short* __restrict__ g_t,
            const float* __restrict__ w_last,
            const float* __restrict__ b_last,
            const float* __restrict__ gamma,
            float* __restrict__ out) {
  __shared__ float cmb[2*32*40];   // [rg][row 0..31][0..31 O-partial, 32 den]
  __shared__ float o_sh[64*33];
  int tid  = threadIdx.x;
  int lane = tid & 63;
  int wv   = tid >> 6;
  int rg   = wv & 1;               // row-group (32 rows each)
  int kh   = wv >> 1;              // key half (512 keys each)
  int r    = lane & 15;
  int q    = lane >> 4;
  int bx = blockIdx.x;
  int b  = bx >> 6;
  int n0 = (bx & 63) * 64;
  int row0 = n0 + rg*32;

  bf16x8 dfrag0 = *(const bf16x8*)(delta_s + ((size_t)b*HW_ + row0 + r)*16      + (q & 1)*8);
  bf16x8 dfrag1 = *(const bf16x8*)(delta_s + ((size_t)b*HW_ + row0 + 16 + r)*16 + (q & 1)*8);

  const unsigned short* phib = phi_s + (size_t)b*M_*16;
  const unsigned short* gb0  = g_t + ((size_t)b*C2_ + r)      * M_;
  const unsigned short* gb1  = g_t + ((size_t)b*C2_ + 16 + r) * M_;
  int phi_off = (q >> 1) * 8;               // [ph ph pl pl] across k
  int key0 = (r >> 2)*8 + (r & 3);          // perm: S-tile C-layout == PV A-frag
  int key1 = key0 + 4;

  bf16x8 ones;
  #pragma unroll
  for (int i = 0; i < 8; ++i) ones[i] = (short)0x3F80;  // bf16 1.0

  f32x4 acc00 = {0,0,0,0}, acc01 = {0,0,0,0};   // tile0 x [c 0..15, c 16..31]
  f32x4 acc10 = {0,0,0,0}, acc11 = {0,0,0,0};   // tile1
  f32x4 accd0 = {0,0,0,0}, accd1 = {0,0,0,0};   // denominators (E . ones)
  f32x4 zero  = {0,0,0,0};

  int kbase = kh * 512;
  #pragma unroll 4
  for (int kc = 0; kc < 512; kc += 32) {
    int k0 = kbase + kc;
    bf16x8 aphi0 = *(const bf16x8*)(phib + (size_t)(k0 + key0)*16 + phi_off);
    bf16x8 aphi1 = *(const bf16x8*)(phib + (size_t)(k0 + key1)*16 + phi_off);
    bf16x8 bg0   = *(const bf16x8*)(gb0 + k0 + q*8);
    bf16x8 bg1   = *(const bf16x8*)(gb1 + k0 + q*8);

    // ---- tile 0
    f32x4 s0 = MFMA_BF16(aphi0, dfrag0, zero, 0, 0, 0);
    f32x4 s1 = MFMA_BF16(aphi1, dfrag0, zero, 0, 0, 0);
    union { bf16x8 v; __hip_bfloat162 h[4]; } e0;
    e0.h[0] = __float22bfloat162_rn(make_float2(__builtin_amdgcn_exp2f(s0[0]),
                                                __builtin_amdgcn_exp2f(s0[1])));
    e0.h[1] = __float22bfloat162_rn(make_float2(__builtin_amdgcn_exp2f(s0[2]),
                                                __builtin_amdgcn_exp2f(s0[3])));
    e0.h[2] = __float22bfloat162_rn(make_float2(__builtin_amdgcn_exp2f(s1[0]),
                                                __builtin_amdgcn_exp2f(s1[1])));
    e0.h[3] = __float22bfloat162_rn(make_float2(__builtin_amdgcn_exp2f(s1[2]),
                                                __builtin_amdgcn_exp2f(s1[3])));
    acc00 = MFMA_BF16(e0.v, bg0, acc00, 0, 0, 0);
    acc01 = MFMA_BF16(e0.v, bg1, acc01, 0, 0, 0);
    accd0 = MFMA_BF16(e0.v, ones, accd0, 0, 0, 0);

    // ---- tile 1 (reuses aphi/bg loads)
    f32x4 t0 = MFMA_BF16(aphi0, dfrag1, zero, 0, 0, 0);
    f32x4 t1 = MFMA_BF16(aphi1, dfrag1, zero, 0, 0, 0);
    union { bf16x8 v; __hip_bfloat162 h[4]; } e1;
    e1.h[0] = __float22bfloat162_rn(make_float2(__builtin_amdgcn_exp2f(t0[0]),
                                                __builtin_amdgcn_exp2f(t0[1])));
    e1.h[1] = __float22bfloat162_rn(make_float2(__builtin_amdgcn_exp2f(t0[2]),
                                                __builtin_amdgcn_exp2f(t0[3])));
    e1.h[2] = __float22bfloat162_rn(make_float2(__builtin_amdgcn_exp2f(t1[0]),
                                                __builtin_amdgcn_exp2f(t1[1])));
    e1.h[3] = __float22bfloat162_rn(make_float2(__builtin_amdgcn_exp2f(t1[2]),
                                                __builtin_amdgcn_exp2f(t1[3])));
    acc10 = MFMA_BF16(e1.v, bg0, acc10, 0, 0, 0);
    acc11 = MFMA_BF16(e1.v, bg1, acc11, 0, 0, 0);
    accd1 = MFMA_BF16(e1.v, ones, accd1, 0, 0, 0);
  }

  // combine the two key-halves through LDS
  if (kh == 1) {
    float* cb = cmb + rg*32*40;
    #pragma unroll
    for (int reg = 0; reg < 4; ++reg) {
      int lr = q*4 + reg;
      cb[lr*40 + r]           = acc00[reg];
      cb[lr*40 + 16 + r]      = acc01[reg];
      cb[(16+lr)*40 + r]      = acc10[reg];
      cb[(16+lr)*40 + 16 + r] = acc11[reg];
      if (r == 0) {
        cb[lr*40 + 32]      = accd0[reg];
        cb[(16+lr)*40 + 32] = accd1[reg];
      }
    }
  }
  __syncthreads();
  if (kh == 0) {
    const float* cb = cmb + rg*32*40;
    #pragma unroll
    for (int reg = 0; reg < 4; ++reg) {
      int lr = q*4 + reg;
      float den0 = accd0[reg] + cb[lr*40 + 32];
      float den1 = accd1[reg] + cb[(16+lr)*40 + 32];
      float i0 = __builtin_amdgcn_rcpf(den0);
      float i1 = __builtin_amdgcn_rcpf(den1);
      o_sh[(rg*32 + lr)*33 + r]           = (acc00[reg] + cb[lr*40 + r])           * i0;
      o_sh[(rg*32 + lr)*33 + 16 + r]      = (acc01[reg] + cb[lr*40 + 16 + r])      * i0;
      o_sh[(rg*32 + 16 + lr)*33 + r]      = (acc10[reg] + cb[(16+lr)*40 + r])      * i1;
      o_sh[(rg*32 + 16 + lr)*33 + 16 + r] = (acc11[reg] + cb[(16+lr)*40 + 16 + r]) * i1;
    }
  }
  __syncthreads();

  // epilogue: out[b,co,n0+rr] = gamma*(w_last[co,:].O[rr,:] + b_last[co]) + x
  int rr = tid & 63;
  int wq = tid >> 6;
  float o_reg[32];
  #pragma unroll
  for (int c = 0; c < 32; ++c) o_reg[c] = o_sh[rr*33 + c];
  float gm = gamma[0];
  for (int i = 0; i < 16; ++i) {
    int co = wq*16 + i;                        // wave-uniform -> scalar loads
    float a = b_last[co];
    #pragma unroll
    for (int c = 0; c < 32; ++c) a += w_last[co*32 + c] * o_reg[c];
    size_t oi = ((size_t)b*C_ + co)*HW_ + (size_t)(n0 + rr);
    out[oi] = gm * a + x[oi];
  }
}

// ---------------------------------------------------------------------------
extern "C" void kernel_launch(void* const* d_in, const int* in_sizes, int n_in,
                              void* d_out, int out_size, void* d_ws, size_t ws_size,
                              hipStream_t stream) {
  const float* x       = (const float*)d_in[0];
  const float* w_delta = (const float*)d_in[1];
  const float* b_delta = (const float*)d_in[2];
  const float* w_phi   = (const float*)d_in[3];
  const float* b_phi   = (const float*)d_in[4];
  const float* w_g     = (const float*)d_in[5];
  const float* b_g     = (const float*)d_in[6];
  const float* w_last  = (const float*)d_in[7];
  const float* b_last  = (const float*)d_in[8];
  const float* gamma   = (const float*)d_in[9];
  float* out = (float*)d_out;

  unsigned short* ws = (unsigned short*)d_ws;
  unsigned short* delta_s = ws;                         // 16*4096*16 = 2 MB
  unsigned short* phi_s   = ws + (size_t)B_*HW_*16;     // 16*1024*16 = 0.5 MB
  unsigned short* g_t     = phi_s + (size_t)B_*M_*16;   // 16*32*1024 = 1 MB

  hipLaunchKernelGGL(k_pre, dim3(1024), dim3(256), 0, stream,
                     x, w_delta, b_delta, w_phi, b_phi, w_g, b_g,
                     delta_s, phi_s, g_t);
  hipLaunchKernelGGL(k_attn, dim3(1024), dim3(256), 0, stream,
                     x, delta_s, phi_s, g_t, w_last, b_last, gamma, out);
}